// Round 1
// baseline (455.264 us; speedup 1.0000x reference)
//
#include <hip/hip_runtime.h>
#include <cmath>

#define EPSF 1e-15f
#define MAXN 0.99999f            // (1 - 1e-5) / sqrt(c), c=1

// ---------------------------------------------------------------------------
// K0: per-pixel logmap0 over channel axis, scaled by beta ratio.
// x layout [B, C, HW]; one thread per (b, pixel).
// ---------------------------------------------------------------------------
template<int C>
__global__ void logmap_chan_kernel(const float* __restrict__ x,
                                   float* __restrict__ out,
                                   int total, int HW, float ratio) {
    int idx = blockIdx.x * blockDim.x + threadIdx.x;
    if (idx >= total) return;
    int b = idx / HW, p = idx % HW;
    const float* xp = x + (size_t)b * C * HW + p;
    float vals[C];
    float n2 = 0.f;
#pragma unroll
    for (int c = 0; c < C; c++) { float v = xp[(size_t)c * HW]; vals[c] = v; n2 += v * v; }
    float n = fmaxf(sqrtf(n2), EPSF);
    float sn = fminf(n, 1.0f - 1e-7f);
    float f = atanhf(sn) / n * ratio;
    float* op = out + (size_t)b * C * HW + p;
#pragma unroll
    for (int c = 0; c < C; c++) op[(size_t)c * HW] = vals[c] * f;
}

// ---------------------------------------------------------------------------
// K1: fused hconv (expmap0(patch) -> poincare_fc) + hrelu(channel) + hmaxpool2.
// v: logmap'd, beta-scaled input [B, CIN, HIN, WIN]. One thread per pooled
// output position; computes the 4 conv outputs of its 2x2 window.
// ---------------------------------------------------------------------------
template<int CIN, int COUT, int HIN, int WIN, int HP, int WP>
__global__ void conv_hrelu_pool_kernel(const float* __restrict__ v,
                                       const float* __restrict__ z,
                                       const float* __restrict__ r,
                                       float* __restrict__ out, int B) {
    constexpr int K = 5;
    constexpr int DIN = CIN * K * K;
    __shared__ float zu_s[DIN][COUT];
    __shared__ float zn_s[COUT], ch_s[COUT], sh_s[COUT];
    int tid = threadIdx.x;
    if (tid < COUT) {
        float s = 0.f;
        for (int f = 0; f < DIN; f++) { float w = z[f * COUT + tid]; s += w * w; }
        float zn = fmaxf(sqrtf(s), EPSF);
        zn_s[tid] = zn;
        float d = 2.0f * r[tid];
        ch_s[tid] = coshf(d);
        sh_s[tid] = sinhf(d);
    }
    __syncthreads();
    for (int e = tid; e < DIN * COUT; e += blockDim.x) {
        int f = e / COUT, o = e % COUT;
        zu_s[f][o] = z[e] / zn_s[o];
    }
    __syncthreads();

    int idx = blockIdx.x * blockDim.x + tid;
    int total = B * HP * WP;
    if (idx >= total) return;
    int b = idx / (HP * WP);
    int pp = idx % (HP * WP);
    int ph = pp / WP, pw = pp % WP;

    float best[COUT];
    float bestn = -1.f;
    const float* vb = v + (size_t)b * CIN * HIN * WIN;

    for (int dy = 0; dy < 2; dy++) {
        for (int dx = 0; dx < 2; dx++) {
            int oy = ph * 2 + dy, ox = pw * 2 + dx;
            float acc[COUT];
#pragma unroll
            for (int o = 0; o < COUT; o++) acc[o] = 0.f;
            float n2 = 0.f;
            for (int c = 0; c < CIN; c++) {
                for (int i = 0; i < K; i++) {
                    const float* row = vb + ((size_t)c * HIN + (oy + i)) * WIN + ox;
                    int fbase = (c * K + i) * K;
#pragma unroll
                    for (int j = 0; j < K; j++) {
                        float val = row[j];
                        n2 += val * val;
#pragma unroll
                        for (int o = 0; o < COUT; o++)
                            acc[o] = fmaf(val, zu_s[fbase + j][o], acc[o]);
                    }
                }
            }
            // expmap0 of the patch (project included)
            float n = fmaxf(sqrtf(n2), EPSF);
            float t = tanhf(n);
            float s = t / n * fminf(1.0f, MAXN / fmaxf(t, EPSF));
            float cx2 = (s * s) * n2;
            float denom = fmaxf(1.0f - cx2, EPSF);
            // poincare_fc
            float y[COUT];
            float ys2 = 0.f;
#pragma unroll
            for (int o = 0; o < COUT; o++) {
                float dot = s * acc[o];
                float arg = (2.0f * dot * ch_s[o] - (1.0f + cx2) * sh_s[o]) / denom;
                float vv = 2.0f * zn_s[o] * asinhf(arg);
                float yy = sinhf(vv);
                y[o] = yy;
                ys2 += yy * yy;
            }
            float dnm = 1.0f + sqrtf(1.0f + ys2);
            float ny2 = 0.f;
#pragma unroll
            for (int o = 0; o < COUT; o++) { y[o] = y[o] / dnm; ny2 += y[o] * y[o]; }
            float ny = fmaxf(sqrtf(ny2), EPSF);
            float pf = fminf(1.0f, MAXN / ny);
            float n2b = 0.f;
#pragma unroll
            for (int o = 0; o < COUT; o++) { y[o] *= pf; n2b += y[o] * y[o]; }
            // hrelu over channels
            float nb = fmaxf(sqrtf(n2b), EPSF);
            float snb = fminf(nb, 1.0f - 1e-7f);
            float fb = atanhf(snb) / nb;
            float u[COUT];
            float m2 = 0.f;
#pragma unroll
            for (int o = 0; o < COUT; o++) {
                float uu = fmaxf(fb * y[o], 0.f);
                u[o] = uu;
                m2 += uu * uu;
            }
            float m = fmaxf(sqrtf(m2), EPSF);
            float tm = tanhf(m);
            float g = tm / m * fminf(1.0f, MAXN / fmaxf(tm, EPSF));
            float hn2 = 0.f;
#pragma unroll
            for (int o = 0; o < COUT; o++) { u[o] *= g; hn2 += u[o] * u[o]; }
            // hmaxpool2: keep max squared-norm, first-max wins (strict >)
            if (hn2 > bestn) {
                bestn = hn2;
#pragma unroll
                for (int o = 0; o < COUT; o++) best[o] = u[o];
            }
        }
    }
    float* ob = out + (size_t)b * COUT * HP * WP + pp;
#pragma unroll
    for (int o = 0; o < COUT; o++) ob[(size_t)o * HP * WP] = best[o];
}

// ---------------------------------------------------------------------------
// K3: row-wise expmap0 (flatten second half). Block (128 thr) per row.
// ---------------------------------------------------------------------------
__global__ void expmap_row_kernel(const float* __restrict__ u,
                                  float* __restrict__ out, int D) {
    int b = blockIdx.x;
    int tid = threadIdx.x;
    __shared__ float red[128];
    float p = 0.f;
    for (int j = tid; j < D; j += 128) { float v = u[(size_t)b * D + j]; p += v * v; }
    red[tid] = p;
    __syncthreads();
    for (int s = 64; s > 0; s >>= 1) {
        if (tid < s) red[tid] += red[tid + s];
        __syncthreads();
    }
    float n2 = red[0];
    float n = fmaxf(sqrtf(n2), EPSF);
    float t = tanhf(n);
    float g = t / n * fminf(1.0f, MAXN / fmaxf(t, EPSF));
    for (int j = tid; j < D; j += 128) out[(size_t)b * D + j] = g * u[(size_t)b * D + j];
}

// ---------------------------------------------------------------------------
// FC prep: per-output-column norm of z, cosh/sinh(2r).
// ---------------------------------------------------------------------------
__global__ void fc_prep_kernel(const float* __restrict__ z, const float* __restrict__ r,
                               int Din, int Dout, float* __restrict__ zn,
                               float* __restrict__ ch, float* __restrict__ sh) {
    int o = blockIdx.x * blockDim.x + threadIdx.x;
    if (o >= Dout) return;
    float s = 0.f;
    for (int f = 0; f < Din; f++) { float w = z[f * Dout + o]; s += w * w; }
    float n = fmaxf(sqrtf(s), EPSF);
    zn[o] = n;
    float d = 2.0f * r[o];
    ch[o] = coshf(d);
    sh[o] = sinhf(d);
}

// ---------------------------------------------------------------------------
// K4: poincare_fc (+ optional hrelu over output dim). Block (128) per row.
// ---------------------------------------------------------------------------
template<int DIN, int DOUT, bool RELU>
__global__ void fc_kernel(const float* __restrict__ x, const float* __restrict__ z,
                          const float* __restrict__ zn, const float* __restrict__ ch,
                          const float* __restrict__ sh, float* __restrict__ out) {
    int b = blockIdx.x, tid = threadIdx.x;
    __shared__ float xs[DIN];
    __shared__ float red[128];

    float p = 0.f;
    for (int j = tid; j < DIN; j += 128) {
        float v = x[(size_t)b * DIN + j];
        xs[j] = v;
        p += v * v;
    }
    red[tid] = p;
    __syncthreads();
    for (int s = 64; s > 0; s >>= 1) { if (tid < s) red[tid] += red[tid + s]; __syncthreads(); }
    float cx2 = red[0];
    __syncthreads();
    float denom = fmaxf(1.0f - cx2, EPSF);

    float yv = 0.f;
    if (tid < DOUT) {
        float dot = 0.f;
        for (int f = 0; f < DIN; f++) dot = fmaf(xs[f], z[f * DOUT + tid], dot);
        dot /= zn[tid];
        float arg = (2.0f * dot * ch[tid] - (1.0f + cx2) * sh[tid]) / denom;
        float vv = 2.0f * zn[tid] * asinhf(arg);
        yv = sinhf(vv);
    }
    red[tid] = (tid < DOUT) ? yv * yv : 0.f;
    __syncthreads();
    for (int s = 64; s > 0; s >>= 1) { if (tid < s) red[tid] += red[tid + s]; __syncthreads(); }
    float ys2 = red[0];
    __syncthreads();
    yv = yv / (1.0f + sqrtf(1.0f + ys2));

    red[tid] = (tid < DOUT) ? yv * yv : 0.f;
    __syncthreads();
    for (int s = 64; s > 0; s >>= 1) { if (tid < s) red[tid] += red[tid + s]; __syncthreads(); }
    float ny = fmaxf(sqrtf(red[0]), EPSF);
    __syncthreads();
    yv *= fminf(1.0f, MAXN / ny);

    if (RELU) {
        red[tid] = (tid < DOUT) ? yv * yv : 0.f;
        __syncthreads();
        for (int s = 64; s > 0; s >>= 1) { if (tid < s) red[tid] += red[tid + s]; __syncthreads(); }
        float n = fmaxf(sqrtf(red[0]), EPSF);
        __syncthreads();
        float sn = fminf(n, 1.0f - 1e-7f);
        float fb = atanhf(sn) / n;
        float u = fmaxf(fb * yv, 0.f);
        red[tid] = (tid < DOUT) ? u * u : 0.f;
        __syncthreads();
        for (int s = 64; s > 0; s >>= 1) { if (tid < s) red[tid] += red[tid + s]; __syncthreads(); }
        float m = fmaxf(sqrtf(red[0]), EPSF);
        __syncthreads();
        float tm = tanhf(m);
        float g = tm / m * fminf(1.0f, MAXN / fmaxf(tm, EPSF));
        yv = g * u;
    }
    if (tid < DOUT) out[(size_t)b * DOUT + tid] = yv;
}

// ---------------------------------------------------------------------------
static double beta_fn(double n) {
    return exp(lgamma(n / 2.0) + lgamma(0.5) - lgamma((n + 1) / 2.0));
}

extern "C" void kernel_launch(void* const* d_in, const int* in_sizes, int n_in,
                              void* d_out, int out_size, void* d_ws, size_t ws_size,
                              hipStream_t stream) {
    (void)in_sizes; (void)n_in; (void)out_size; (void)ws_size;
    const float* x   = (const float*)d_in[0];
    const float* z1  = (const float*)d_in[1];
    const float* b1  = (const float*)d_in[2];
    const float* z2  = (const float*)d_in[3];
    const float* b2  = (const float*)d_in[4];
    const float* zf1 = (const float*)d_in[5];
    const float* bf1 = (const float*)d_in[6];
    const float* zf2 = (const float*)d_in[7];
    const float* bf2 = (const float*)d_in[8];
    const float* zf3 = (const float*)d_in[9];
    const float* bf3 = (const float*)d_in[10];
    float* out = (float*)d_out;
    float* ws  = (float*)d_ws;

    const int B = 1024;

    // workspace layout (floats); region A reused once v1 is dead
    float* v1   = ws;                         // [B,3,32,32]  = 3145728
    float* v2   = ws;                         // [B,6,14,14]  = 1204224 (reuse)
    float* u3   = ws + 1204224;               // [B,400]      = 409600
    float* buf3 = ws + 1613824;               // [B,400]
    float* buf4 = ws + 2023424;               // [B,120]      = 122880
    float* buf5 = ws + 2146304;               // [B,84]       = 86016
    float* buf1 = ws + 3145728;               // [B,6,14,14]  = 1204224
    float* buf2 = ws + 3145728 + 1204224;     // [B,16,5,5]   = 409600
    float* prep = ws + 3145728 + 1204224 + 409600;
    float* zn1 = prep;       float* ch1 = prep + 120; float* sh1 = prep + 240;
    float* zn2 = prep + 360; float* ch2 = prep + 444; float* sh2 = prep + 528;
    float* zn3 = prep + 612; float* ch3 = prep + 622; float* sh3 = prep + 632;

    const float ratio1 = (float)(beta_fn(75.0)  / beta_fn(3.0));
    const float ratio2 = (float)(beta_fn(150.0) / beta_fn(6.0));
    const float ratio3 = (float)(beta_fn(400.0) / beta_fn(16.0));

    // FC preps (depend only on weights; run first)
    fc_prep_kernel<<<1, 128, 0, stream>>>(zf1, bf1, 400, 120, zn1, ch1, sh1);
    fc_prep_kernel<<<1, 128, 0, stream>>>(zf2, bf2, 120, 84, zn2, ch2, sh2);
    fc_prep_kernel<<<1, 64,  0, stream>>>(zf3, bf3, 84, 10, zn3, ch3, sh3);

    // stage 1: conv1 -> hrelu -> pool
    logmap_chan_kernel<3><<<(B * 1024 + 255) / 256, 256, 0, stream>>>(x, v1, B * 1024, 1024, ratio1);
    conv_hrelu_pool_kernel<3, 6, 32, 32, 14, 14><<<(B * 196 + 255) / 256, 256, 0, stream>>>(v1, z1, b1, buf1, B);

    // stage 2: conv2 -> hrelu -> pool
    logmap_chan_kernel<6><<<(B * 196 + 255) / 256, 256, 0, stream>>>(buf1, v2, B * 196, 196, ratio2);
    conv_hrelu_pool_kernel<6, 16, 14, 14, 5, 5><<<(B * 25 + 255) / 256, 256, 0, stream>>>(v2, z2, b2, buf2, B);

    // stage 3: hflatten
    logmap_chan_kernel<16><<<(B * 25 + 255) / 256, 256, 0, stream>>>(buf2, u3, B * 25, 25, ratio3);
    expmap_row_kernel<<<B, 128, 0, stream>>>(u3, buf3, 400);

    // stage 4-6: FC layers
    fc_kernel<400, 120, true ><<<B, 128, 0, stream>>>(buf3, zf1, zn1, ch1, sh1, buf4);
    fc_kernel<120, 84,  true ><<<B, 128, 0, stream>>>(buf4, zf2, zn2, ch2, sh2, buf5);
    fc_kernel<84,  10,  false><<<B, 128, 0, stream>>>(buf5, zf3, zn3, ch3, sh3, out);
}